// Round 1
// 607.782 us; speedup vs baseline: 1.0453x; 1.0453x over previous
//
#include <hip/hip_runtime.h>
#include <hip/hip_bf16.h>

typedef __bf16 bf16x8 __attribute__((ext_vector_type(8)));
typedef float  f32x4  __attribute__((ext_vector_type(4)));

#define MFMA16(a,b,c) __builtin_amdgcn_mfma_f32_16x16x32_bf16((a),(b),(c),0,0,0)

__device__ __forceinline__ bf16x8 cvt8(f32x4 a, f32x4 b){
  bf16x8 r;
  r[0]=(__bf16)a[0]; r[1]=(__bf16)a[1]; r[2]=(__bf16)a[2]; r[3]=(__bf16)a[3];
  r[4]=(__bf16)b[0]; r[5]=(__bf16)b[1]; r[6]=(__bf16)b[2]; r[7]=(__bf16)b[3];
  return r;
}
__device__ __forceinline__ bf16x8 ld8(const float* p){
  return cvt8(*(const f32x4*)p, *(const f32x4*)(p+4));
}
__device__ __forceinline__ float sigm(float x){
  return __builtin_amdgcn_rcpf(1.f + __expf(-x));
}
__device__ __forceinline__ float tanhx(float x){
  return 1.f - 2.f*__builtin_amdgcn_rcpf(1.f + __expf(2.f*x));
}
__device__ __forceinline__ f32x4 sp(float v){ return (f32x4){v,v,v,v}; }

// lane^8 exchange within each 16-lane row: DPP row_ror:8 (VALU pipe, no LDS)
__device__ __forceinline__ float dppx8(float v){
  return __int_as_float(__builtin_amdgcn_update_dpp(
      0, __float_as_int(v), 0x128, 0xF, 0xF, true));
}
// lane^4 exchange: ds_swizzle xor-4 (decoder only, 96 phases total)
__device__ __forceinline__ float swz4(float v){
  return __int_as_float(__builtin_amdgcn_ds_swizzle(__float_as_int(v), 0x101F));
}

// Fused GEMM+EW, layer-split, 16 waves: waves 0-7 layer0, 8-15 layer1.
// Gate-column permutation: wave owns ALL 4 gates of 8 units
//   tile0 cols = [i(u0..u0+7) | f(u0..u0+7)], tile1 = [g(..) | o(..)]
// so after MFMA one DPP xor-8 + cndmask selects give each lane its own
// (i,f,g,o) -> EW in-register. Gate LDS round-trip (old Gm) eliminated;
// ONE barrier per LSTM slot instead of two.
// Strides: XA 136 bf16 = 68 dw, H1s 72 bf16 = 36 dw -- both == 4 mod 32 so the
// scattered bf16 h-store (rows 0..7 x 8 consecutive units) is 2-way (free).
extern "C" __global__ void __launch_bounds__(1024, 4)
seq2seq_kernel(const float* __restrict__ X,
               const float* __restrict__ Wemb, const float* __restrict__ bemb,
               const float* __restrict__ eWih, const float* __restrict__ eWhh,
               const float* __restrict__ ebih, const float* __restrict__ ebhh,
               const float* __restrict__ dWih, const float* __restrict__ dWhh,
               const float* __restrict__ dbih, const float* __restrict__ dbhh,
               const float* __restrict__ Wreg, const float* __restrict__ breg,
               float* __restrict__ out)
{
  // XA[parity][row][136]: cols 0-63 = x/input, 64-127 = h0. h1 double-buffered.
  __shared__ __align__(16) __bf16 XA[2][8][136];
  __shared__ __align__(16) __bf16 H1s[2][8][72];

  const int tid  = (int)threadIdx.x;
  const int w    = tid >> 6;         // 0..15
  const int grp  = w >> 3;           // 0: layer0 group, 1: layer1 group
  const bool g0  = (grp == 0);
  const int wt   = w & 7;            // wave-in-group; units u0 = 8*wt
  const int lane = tid & 63;
  const int col  = lane & 15;
  const int quad = lane >> 4;
  const int row8 = col & 7;          // A real row (M=16 mirrors 8 rows)
  const int b0   = (int)blockIdx.x * 8;
  const int brow = b0 + row8;

  // fused-EW lane roles (encoder): cell = (row ewr, unit ewu), elem index sr
  const bool hib = (col & 8) != 0;       // sr bit0
  const bool qhb = (quad & 2) != 0;      // sr bit1
  const int  ewr = 4*(quad & 1) + (hib ? 1 : 0) + (qhb ? 2 : 0);
  const int  ewu = 8*wt + (col & 7);

  for (int i = tid; i < 2*8*136; i += 1024) (&XA[0][0][0])[i]  = (__bf16)0.f;
  for (int i = tid; i < 2*8*72;  i += 1024) (&H1s[0][0][0])[i] = (__bf16)0.f;

  // ---- persistent fragments: 2 tiles x 4 ksteps = 32 regs ----
  // gate-permuted col: n = 64*gate + unit, gate = 2*ti + (col>>3)
  bf16x8 wf[8];
  float  gb[2];
#pragma unroll
  for (int ti=0; ti<2; ++ti){
    const int n = 64*(2*ti + (col>>3)) + 8*wt + (col&7);
    gb[ti] = ebih[grp*256+n] + ebhh[grp*256+n];
#pragma unroll
    for (int ks=0; ks<4; ++ks){
      const float* srcw = (ks < 2) ? eWih : eWhh;
      wf[ti*4+ks] = ld8(srcw + ((size_t)(grp*256+n))*64 + (ks&1)*32 + quad*8);
    }
  }

  // emb fragments: only waves 0-3 use them
  const int ue = (w&3)*16 + col;
  bf16x8 wembf;
  float eb = 0.f;
  const float* xb = X + (size_t)brow*512*32 + quad*8;
  f32x4 pa0, pb0, pa1, pb1;
  if (w < 4){
    wembf = ld8(Wemb + ue*32 + quad*8);
    eb = bemb[ue];
    pa1 = *(const f32x4*)(xb+32); pb1 = *(const f32x4*)(xb+36);   // x(1)
    pa0 = *(const f32x4*)(xb+64); pb0 = *(const f32x4*)(xb+68);   // x(2)
  }

  float cC = 0.f;   // grp0: c0 of cell (ewr,ewu); grp1: c1

  // in-register EW: gather (i,f,g,o) for this lane's cell via DPP xor-8.
  // lane c<8 locally holds (i,g) at elem sr; c>=8 holds (f,o); partner c^8
  // sends its elem sr^1 (== my sr, same real row).
  auto EWF = [&](f32x4 A0, f32x4 A1, float& c) -> float {
    float lo0 = qhb ? A0[2] : A0[0];
    float hi0 = qhb ? A0[3] : A0[1];
    float lo1 = qhb ? A1[2] : A1[0];
    float hi1 = qhb ? A1[3] : A1[1];
    float a0s = hib ? hi0 : lo0, a0x = hib ? lo0 : hi0;
    float a1s = hib ? hi1 : lo1, a1x = hib ? lo1 : hi1;
    float r0 = dppx8(a0x), r1 = dppx8(a1x);
    float gi = hib ? r0  : a0s;
    float gf = hib ? a0s : r0;
    float gg = hib ? r1  : a1s;
    float go = hib ? a1s : r1;
    float i0 = sigm(gi), f0 = sigm(gf), gt = tanhx(gg), o0 = sigm(go);
    c = f0*c + i0*gt;
    return o0*tanhx(c);
  };

  // grp0 slot I: gates+cells of L0(I+1) -> h0(I+1) at parity (I+1)&1;
  //             emb(I+2) -> XA[I&1].x (waves 0-3)
  auto FUSED0 = [&](const int I){
    const int Px = (I+1)&1, Pr = I&1;
    bf16x8 ax0 = *(const bf16x8*)&XA[Px][row8][ 0 + quad*8];
    bf16x8 ax1 = *(const bf16x8*)&XA[Px][row8][32 + quad*8];
    bf16x8 ah0 = *(const bf16x8*)&XA[Pr][row8][64 + quad*8];
    bf16x8 ah1 = *(const bf16x8*)&XA[Pr][row8][96 + quad*8];
    f32x4 A0 = sp(gb[0]), A1 = sp(gb[1]);
    A0=MFMA16(ax0,wf[0],A0); A1=MFMA16(ax0,wf[4],A1);
    A0=MFMA16(ax1,wf[1],A0); A1=MFMA16(ax1,wf[5],A1);
    A0=MFMA16(ah0,wf[2],A0); A1=MFMA16(ah0,wf[6],A1);
    A0=MFMA16(ah1,wf[3],A0); A1=MFMA16(ah1,wf[7],A1);
    if (I < 510 && w < 4){
      const int s = I&1;
      f32x4 xr0 = s ? pa1 : pa0, xr1 = s ? pb1 : pb0;
      f32x4 ea = MFMA16(cvt8(xr0,xr1), wembf, sp(eb));
      int tn = I+4; if (tn > 511) tn = 511;
      f32x4 na = *(const f32x4*)(xb + (size_t)tn*32);
      f32x4 nb = *(const f32x4*)(xb + (size_t)tn*32 + 4);
      if (s){ pa1=na; pb1=nb; } else { pa0=na; pb0=nb; }
      if (quad < 2){
#pragma unroll
        for (int r=0; r<4; ++r) XA[s][quad*4+r][ue] = (__bf16)ea[r];
      }
    }
    XA[Px][ewr][64+ewu] = (__bf16)EWF(A0, A1, cC);
  };

  // grp1 slot I: L1(I) = [h0(I) | h1(I-1)] -> h1(I) at parity I&1
  auto FUSED1 = [&](const int I){
    const int Px = (I+1)&1, Pr = I&1;     // Px == (I-1)&1 too
    bf16x8 ah0 = *(const bf16x8*)&XA[Pr][row8][64 + quad*8];
    bf16x8 ah1 = *(const bf16x8*)&XA[Pr][row8][96 + quad*8];
    bf16x8 ag0 = *(const bf16x8*)&H1s[Px][row8][ 0 + quad*8];
    bf16x8 ag1 = *(const bf16x8*)&H1s[Px][row8][32 + quad*8];
    f32x4 A0 = sp(gb[0]), A1 = sp(gb[1]);
    A0=MFMA16(ah0,wf[0],A0); A1=MFMA16(ah0,wf[4],A1);
    A0=MFMA16(ah1,wf[1],A0); A1=MFMA16(ah1,wf[5],A1);
    A0=MFMA16(ag0,wf[2],A0); A1=MFMA16(ag0,wf[6],A1);
    A0=MFMA16(ag1,wf[3],A0); A1=MFMA16(ag1,wf[7],A1);
    H1s[Pr][ewr][ewu] = (__bf16)EWF(A0, A1, cC);
  };

  __syncthreads();                 // zero-init visible

  // ---- prologue: emb(0), then h0(0) ----
  if (w < 4){
    f32x4 x0a = *(const f32x4*)xb, x0b = *(const f32x4*)(xb+4);
    f32x4 e0 = MFMA16(cvt8(x0a,x0b), wembf, sp(eb));
    if (quad < 2){
#pragma unroll
      for (int r=0; r<4; ++r) XA[0][quad*4+r][ue] = (__bf16)e0[r];
    }
  }
  __syncthreads();
  if (g0) FUSED0(-1);              // h0(0) -> parity 0; emb(1) -> XA[1].x
  __syncthreads();

  // ---- steady encoder: slot I -> h0(I+1) & h1(I); ONE barrier/slot ----
#define SLOT(I) { if (g0) FUSED0(I); else FUSED1(I); __syncthreads(); }
  for (int ii=0; ii<255; ++ii){
    SLOT(2*ii)
    SLOT(2*ii+1)
  }
  SLOT(510)
#undef SLOT

  // ---- epilogue: h1(511) ----
  if (!g0) FUSED1(511);            // reads h0(511) (par 1), h1(510) (par 0)
  __syncthreads();

  // ================= decoder =================
  // init: XA[1] = [input=h1(511) | h0(511)] (h0(511) already at XA[1][64..])
  for (int idx = tid; idx < 8*64; idx += 1024){
    XA[1][idx>>6][idx&63] = H1s[1][idx>>6][idx&63];
  }
  // regression head (loaded late to keep encoder reg pressure low)
  bf16x8 wr0 = ld8(Wreg + (col&7)*64 +  0 + quad*8);
  bf16x8 wr1 = ld8(Wreg + (col&7)*64 + 32 + quad*8);
  const float rb = breg[col&7];
  // decoder: wave w owns 4 units (both layers), 16 gate-permuted cols:
  // col = [i(4) | f(4) | g(4) | o(4)], n = 64*(col>>2) + 4*w + (col&3)
  float gbd[2];
#pragma unroll
  for (int l=0; l<2; ++l){
    const int n = 64*(col>>2) + 4*w + (col&3);
    gbd[l] = dbih[l*256+n] + dbhh[l*256+n];
#pragma unroll
    for (int ks=0; ks<4; ++ks){
      const float* srcw = (ks < 2) ? dWih : dWhh;
      wf[l*4+ks] = ld8(srcw + ((size_t)(l*256+n))*64 + (ks&1)*32 + quad*8);
    }
  }
  // decoder fused-EW lane roles: gate = col>>2; 2x redundancy, writer = even gate
  const int  gated = col >> 2;
  const bool b0d = (gated & 1) != 0;
  const bool b1d = (gated & 2) != 0;     // sr bit0
  const int  rd  = 4*(quad & 1) + (b1d ? 1 : 0) + (qhb ? 2 : 0);
  const int  udj = 4*w + (col & 3);
  float cD0 = 0.f, cD1 = 0.f;
  __syncthreads();

  // 4-gate gather: xor-4 (swz) for gate^1, xor-8 (DPP) for gate^2/^3
  auto EWD = [&](f32x4 B, float& c) -> float {
    float lo  = qhb ? B[2] : B[0];
    float hi2 = qhb ? B[3] : B[1];
    float a  = b1d ? hi2 : lo;           // own gate, elem sr
    float ax = b1d ? lo  : hi2;          // own gate, elem sr^1
    float pA = swz4(a);                  // gate^1 @ sr
    float pB = swz4(ax);                 // gate^1 @ sr^1
    float qA = dppx8(ax);                // gate^2 @ sr
    float qB = dppx8(pB);                // gate^3 @ sr
    float gi = b1d ? (b0d?qB:qA) : (b0d?pA:a);
    float gf = b1d ? (b0d?qA:qB) : (b0d?a:pA);
    float gg = b1d ? (b0d?pA:a) : (b0d?qB:qA);
    float go = b1d ? (b0d?a:pA) : (b0d?qA:qB);
    float i0 = sigm(gi), f0 = sigm(gf), gt = tanhx(gg), o0 = sigm(go);
    c = f0*c + i0*gt;
    return o0*tanhx(c);
  };

  auto Ystore = [&](const int t){
    const int hp = t&1;
    f32x4 ya = sp(rb);
    bf16x8 y0 = *(const bf16x8*)&H1s[hp][row8][ 0 + quad*8];
    bf16x8 y1 = *(const bf16x8*)&H1s[hp][row8][32 + quad*8];
    ya = MFMA16(y0, wr0, ya);
    ya = MFMA16(y1, wr1, ya);
    if (quad < 2 && col < 8){
#pragma unroll
      for (int r=0; r<4; ++r)
        out[((size_t)(b0 + quad*4 + r)*48 + t)*8 + col] = ya[r];
    }
  };

  // per step: 2 fused phases (was 4). h0/h1/input all parity-double-buffered.
#define DSTEP(T) {                                                         \
    const int P = (T)&1, Pm = P^1;                                         \
    {                                                                      \
      bf16x8 ax0 = *(const bf16x8*)&XA[Pm][row8][ 0 + quad*8];             \
      bf16x8 ax1 = *(const bf16x8*)&XA[Pm][row8][32 + quad*8];             \
      bf16x8 ah0 = *(const bf16x8*)&XA[Pm][row8][64 + quad*8];             \
      bf16x8 ah1 = *(const bf16x8*)&XA[Pm][row8][96 + quad*8];             \
      f32x4 B0 = sp(gbd[0]);                                               \
      B0=MFMA16(ax0,wf[0],B0); B0=MFMA16(ax1,wf[1],B0);                    \
      B0=MFMA16(ah0,wf[2],B0); B0=MFMA16(ah1,wf[3],B0);                    \
      float h = EWD(B0, cD0);                                              \
      if (!b0d) XA[P][rd][64+udj] = (__bf16)h;                             \
      if ((T) && w == 0) Ystore((T)-1);                                    \
    }                                                                      \
    __syncthreads();                                                       \
    {                                                                      \
      bf16x8 ah0 = *(const bf16x8*)&XA[P][row8][64 + quad*8];              \
      bf16x8 ah1 = *(const bf16x8*)&XA[P][row8][96 + quad*8];              \
      bf16x8 ag0 = *(const bf16x8*)&H1s[Pm][row8][ 0 + quad*8];            \
      bf16x8 ag1 = *(const bf16x8*)&H1s[Pm][row8][32 + quad*8];            \
      f32x4 B1 = sp(gbd[1]);                                               \
      B1=MFMA16(ah0,wf[4],B1); B1=MFMA16(ah1,wf[5],B1);                    \
      B1=MFMA16(ag0,wf[6],B1); B1=MFMA16(ag1,wf[7],B1);                    \
      float h = EWD(B1, cD1);                                              \
      if (!b0d){ H1s[P][rd][udj] = (__bf16)h; XA[P][rd][udj] = (__bf16)h; }\
    }                                                                      \
    __syncthreads();                                                       \
  }

  for (int tt=0; tt<24; ++tt){
    DSTEP(2*tt)
    DSTEP(2*tt+1)
  }
#undef DSTEP
  if (w == 0) Ystore(47);
}

extern "C" void kernel_launch(void* const* d_in, const int* in_sizes, int n_in,
                              void* d_out, int out_size, void* d_ws, size_t ws_size,
                              hipStream_t stream)
{
  (void)in_sizes; (void)n_in; (void)out_size; (void)d_ws; (void)ws_size;
  const float* X    = (const float*)d_in[0];
  const float* Wemb = (const float*)d_in[2];
  const float* bemb = (const float*)d_in[3];
  const float* eWih = (const float*)d_in[4];
  const float* eWhh = (const float*)d_in[5];
  const float* ebih = (const float*)d_in[6];
  const float* ebhh = (const float*)d_in[7];
  const float* dWih = (const float*)d_in[8];
  const float* dWhh = (const float*)d_in[9];
  const float* dbih = (const float*)d_in[10];
  const float* dbhh = (const float*)d_in[11];
  const float* Wreg = (const float*)d_in[12];
  const float* breg = (const float*)d_in[13];
  float* out = (float*)d_out;

  seq2seq_kernel<<<dim3(256), dim3(1024), 0, stream>>>(
      X, Wemb, bemb, eWih, eWhh, ebih, ebhh,
      dWih, dWhh, dbih, dbhh, Wreg, breg, out);
}